// Round 1
// baseline (204.482 us; speedup 1.0000x reference)
//
#include <hip/hip_runtime.h>
#include <stdint.h>

#define B_ROWS 32768
#define N_INP 256
#define N_HID 1024
#define NF 256
#define N_IT 100

typedef __attribute__((ext_vector_type(8))) _Float16 f16x8;
typedef __attribute__((ext_vector_type(4))) float f32x4;

__device__ __forceinline__ ushort f2h(float f) {
  _Float16 h = (_Float16)f;               // v_cvt_f16_f32, RNE
  return *reinterpret_cast<ushort*>(&h);
}

__device__ __forceinline__ void async_copy16(const void* g, void* l) {
  __builtin_amdgcn_global_load_lds(
      (const __attribute__((address_space(1))) void*)g,
      (__attribute__((address_space(3))) void*)l, 16, 0, 0);
}

// ---- prepass: pack x -> f16 [B,256], extract idx; convert W1/W2 -> f16 ----
__global__ void prep_x_kernel(const float* __restrict__ x,
                              ushort* __restrict__ xh,
                              int* __restrict__ idx) {
  int t = blockIdx.x * blockDim.x + threadIdx.x;     // B*64 threads
  int b = t >> 6, q = t & 63;
  const float* xr = x + (size_t)b * (N_INP + 1);
  float v0 = xr[q * 4 + 0], v1 = xr[q * 4 + 1], v2 = xr[q * 4 + 2], v3 = xr[q * 4 + 3];
  ushort4 u = make_ushort4(f2h(v0), f2h(v1), f2h(v2), f2h(v3));
  *reinterpret_cast<ushort4*>(xh + (size_t)b * 256 + q * 4) = u;
  if (q == 0) idx[b] = (int)rintf(xr[N_INP] * 255.0f);
}

__global__ void prep_w_kernel(const float* __restrict__ W1,
                              const float* __restrict__ W2,
                              ushort* __restrict__ w1h,
                              ushort* __restrict__ w2h) {
  int t = blockIdx.x * blockDim.x + threadIdx.x;     // 65536 threads
  float4 a = reinterpret_cast<const float4*>(W1)[t];
  float4 b = reinterpret_cast<const float4*>(W2)[t];
  reinterpret_cast<ushort4*>(w1h)[t] = make_ushort4(f2h(a.x), f2h(a.y), f2h(a.z), f2h(a.w));
  reinterpret_cast<ushort4*>(w2h)[t] = make_ushort4(f2h(b.x), f2h(b.y), f2h(b.z), f2h(b.w));
}

// ---- C[M,N] = epi(A[M,K] @ Bw[N,K]^T + bias) ----
// EPI=1: relu -> f16 store (GEMM1 -> h). EPI=2: f32 store (GEMM2 -> x_).
template <int EPI>
__global__ __launch_bounds__(256, 2) void gemm_bt(
    const ushort* __restrict__ A, const ushort* __restrict__ Bw,
    const float* __restrict__ bias, void* __restrict__ C,
    int M, int N, int K, int ntN) {
  __shared__ ushort As[2][128 * 64];
  __shared__ ushort Bs[2][128 * 64];
  const int tid = threadIdx.x;
  const int w = tid >> 6, l = tid & 63;
  const int tm = blockIdx.x / ntN, tn = blockIdx.x % ntN;
  const int wm = w >> 1, wn = w & 1;
  const char* Ab = (const char*)(A + (size_t)tm * 128 * K);
  const char* Bb = (const char*)(Bw + (size_t)tn * 128 * K);
  const int sA = K * 2;
  const int lrow = l >> 3;
  const int lcol = (l & 7) * 16;

  f32x4 acc[4][4];
#pragma unroll
  for (int i = 0; i < 4; ++i)
#pragma unroll
    for (int j = 0; j < 4; ++j) acc[i][j] = {0.f, 0.f, 0.f, 0.f};

  const int nkt = K / 64;
  {  // prologue stage kt=0
    const char* ga = Ab + lrow * sA + lcol;
    const char* gb = Bb + lrow * sA + lcol;
#pragma unroll
    for (int i = 0; i < 4; ++i) {
      int c = w * 4 + i;
      async_copy16(ga + c * 8 * sA, (char*)&As[0][0] + c * 1024);
      async_copy16(gb + c * 8 * sA, (char*)&Bs[0][0] + c * 1024);
    }
  }
  __syncthreads();  // compiler drains vmcnt before s_barrier

  const int arow = wm * 64 + (l & 15);
  const int brow = wn * 64 + (l & 15);
  const int koff = (l >> 4) * 8;

  for (int kt = 0; kt < nkt; ++kt) {
    const int buf = kt & 1;
    if (kt + 1 < nkt) {  // stage next tile into other buffer
      const char* ga = Ab + (kt + 1) * 128 + lrow * sA + lcol;
      const char* gb = Bb + (kt + 1) * 128 + lrow * sA + lcol;
#pragma unroll
      for (int i = 0; i < 4; ++i) {
        int c = w * 4 + i;
        async_copy16(ga + c * 8 * sA, (char*)&As[buf ^ 1][0] + c * 1024);
        async_copy16(gb + c * 8 * sA, (char*)&Bs[buf ^ 1][0] + c * 1024);
      }
    }
#pragma unroll
    for (int ks = 0; ks < 2; ++ks) {
      f16x8 af[4], bfr[4];
#pragma unroll
      for (int mi = 0; mi < 4; ++mi)
        af[mi] = *(const f16x8*)&As[buf][(arow + mi * 16) * 64 + ks * 32 + koff];
#pragma unroll
      for (int ni = 0; ni < 4; ++ni)
        bfr[ni] = *(const f16x8*)&Bs[buf][(brow + ni * 16) * 64 + ks * 32 + koff];
#pragma unroll
      for (int mi = 0; mi < 4; ++mi)
#pragma unroll
        for (int ni = 0; ni < 4; ++ni)
          acc[mi][ni] = __builtin_amdgcn_mfma_f32_16x16x32_f16(
              af[mi], bfr[ni], acc[mi][ni], 0, 0, 0);
    }
    __syncthreads();
  }

  // epilogue: C/D layout col=lane&15, row=(lane>>4)*4+r (m89/m91 verified)
  const int grow0 = tm * 128 + wm * 64 + (l >> 4) * 4;
  const int gcol0 = tn * 128 + wn * 64 + (l & 15);
#pragma unroll
  for (int ni = 0; ni < 4; ++ni) {
    const int col = gcol0 + ni * 16;
    const float bv = bias[col];
#pragma unroll
    for (int mi = 0; mi < 4; ++mi) {
      const int row = grow0 + mi * 16;
#pragma unroll
      for (int r = 0; r < 4; ++r) {
        float v = acc[mi][ni][r] + bv;
        if (EPI == 1) {
          v = fmaxf(v, 0.f);
          ((ushort*)C)[(size_t)(row + r) * N + col] = f2h(v);
        } else {
          ((float*)C)[(size_t)(row + r) * N + col] = v;
        }
      }
    }
  }
}

// ---- convex fixed-point (100 iters) + gather. One wave per row. ----
// zx = z + p; t_i = zx_i - 0.5*(zx_{i-1}+zx_{i+1});  z_i -= max(t_i, 0)
// (Dz = 2*t, so Dz>0 <=> t>0; dx = zx-mz = t). Rows 0,255: D rows zeroed -> no update.
__global__ __launch_bounds__(256) void convex_gather(
    const float* __restrict__ xq, const int* __restrict__ idx,
    float* __restrict__ out) {
  const int w = threadIdx.x >> 6, l = threadIdx.x & 63;
  const int b = blockIdx.x * 4 + w;
  const float4 p4 = *reinterpret_cast<const float4*>(xq + (size_t)b * 256 + l * 4);
  float p0 = p4.x, p1 = p4.y, p2 = p4.z, p3 = p4.w;
  float z0 = 0.f, z1 = 0.f, z2 = 0.f, z3 = 0.f;
  // boundary sentinels: feat 0 (lane0,j0) and feat 255 (lane63,j3) never update
  const float bL = (l == 0) ? 3.0e38f : 0.0f;
  const float bR = (l == 63) ? 3.0e38f : 0.0f;
  for (int it = 0; it < N_IT; ++it) {
    float zx0 = z0 + p0, zx1 = z1 + p1, zx2 = z2 + p2, zx3 = z3 + p3;
    float L = __shfl_up(zx3, 1) + bL;    // feat 4l-1
    float R = __shfl_down(zx0, 1) + bR;  // feat 4l+4
    float t0 = zx0 - 0.5f * (L + zx1);
    float t1 = zx1 - 0.5f * (zx0 + zx2);
    float t2 = zx2 - 0.5f * (zx1 + zx3);
    float t3 = zx3 - 0.5f * (zx2 + R);
    z0 -= fmaxf(t0, 0.f);
    z1 -= fmaxf(t1, 0.f);
    z2 -= fmaxf(t2, 0.f);
    z3 -= fmaxf(t3, 0.f);
  }
  const int ii = idx[b];  // wave-uniform
  float r0 = p0 + z0, r1 = p1 + z1, r2 = p2 + z2, r3 = p3 + z3;
  float s01 = (ii & 1) ? r1 : r0;
  float s23 = (ii & 1) ? r3 : r2;
  float rs = (ii & 2) ? s23 : s01;
  float v = __shfl(rs, ii >> 2);
  if (l == 0) out[b] = v;
}

extern "C" void kernel_launch(void* const* d_in, const int* in_sizes, int n_in,
                              void* d_out, int out_size, void* d_ws, size_t ws_size,
                              hipStream_t stream) {
  const float* x = (const float*)d_in[0];
  const float* W1 = (const float*)d_in[1];
  const float* b1 = (const float*)d_in[2];
  const float* W2 = (const float*)d_in[3];
  const float* b2 = (const float*)d_in[4];
  float* out = (float*)d_out;

  // workspace layout (all 16B-aligned offsets)
  char* ws = (char*)d_ws;
  ushort* xh  = (ushort*)ws;                    // 16,777,216 B  x as f16 [B,256]
  ushort* w1h = (ushort*)(ws + 16777216);       //    524,288 B
  ushort* w2h = (ushort*)(ws + 17301504);       //    524,288 B
  int*    idx = (int*)  (ws + 17825792);        //    131,072 B
  float*  xq  = (float*)(ws + 17956864);        // 33,554,432 B  x_ f32 [B,256]
  ushort* h   = (ushort*)(ws + 51511296);       // chunk*2048 B  h f16 [chunk,1024]

  const size_t fixed = 51511296;
  int chunk = 2048;
  if (ws_size >= fixed + (size_t)16384 * 2048) chunk = 16384;
  else if (ws_size >= fixed + (size_t)8192 * 2048) chunk = 8192;
  else if (ws_size >= fixed + (size_t)4096 * 2048) chunk = 4096;

  prep_x_kernel<<<(B_ROWS * 64) / 256, 256, 0, stream>>>(x, xh, idx);
  prep_w_kernel<<<65536 / 256, 256, 0, stream>>>(W1, W2, w1h, w2h);

  for (int m0 = 0; m0 < B_ROWS; m0 += chunk) {
    int curM = (B_ROWS - m0 < chunk) ? (B_ROWS - m0) : chunk;
    dim3 g1((curM / 128) * (N_HID / 128));
    gemm_bt<1><<<g1, 256, 0, stream>>>(xh + (size_t)m0 * 256, w1h, b1, h,
                                       curM, N_HID, N_INP, N_HID / 128);
    dim3 g2((curM / 128) * (NF / 128));
    gemm_bt<2><<<g2, 256, 0, stream>>>(h, w2h, b2, xq + (size_t)m0 * 256,
                                       curM, NF, N_HID, NF / 128);
  }
  convex_gather<<<B_ROWS / 4, 256, 0, stream>>>(xq, idx, out);
}

// Round 2
// 144.673 us; speedup vs baseline: 1.4134x; 1.4134x over previous
//
#include <hip/hip_runtime.h>
#include <stdint.h>

#define B_ROWS 32768
#define N_INP 256
#define N_HID 1024
#define NF 256
#define N_IT 100

typedef __attribute__((ext_vector_type(8))) _Float16 f16x8;
typedef __attribute__((ext_vector_type(4))) float f32x4;

__device__ __forceinline__ ushort f2h(float f) {
  _Float16 h = (_Float16)f;               // v_cvt_f16_f32, RNE
  return *reinterpret_cast<ushort*>(&h);
}

__device__ __forceinline__ void async_copy16(const void* g, void* l) {
  __builtin_amdgcn_global_load_lds(
      (const __attribute__((address_space(1))) void*)g,
      (__attribute__((address_space(3))) void*)l, 16, 0, 0);
}

// ---- prepass (fused): pack x -> f16 [B,256] + idx; convert W1/W2 -> f16 ----
// blocks [0,8192): x rows; blocks [8192,8448): weights
__global__ void prep_kernel(const float* __restrict__ x,
                            const float* __restrict__ W1,
                            const float* __restrict__ W2,
                            ushort* __restrict__ xh,
                            ushort* __restrict__ w1h,
                            ushort* __restrict__ w2h,
                            int* __restrict__ idx) {
  if (blockIdx.x < 8192) {
    int t = blockIdx.x * 256 + threadIdx.x;          // B*64 threads
    int b = t >> 6, q = t & 63;
    const float* xr = x + (size_t)b * (N_INP + 1);
    float v0 = xr[q * 4 + 0], v1 = xr[q * 4 + 1], v2 = xr[q * 4 + 2], v3 = xr[q * 4 + 3];
    ushort4 u = make_ushort4(f2h(v0), f2h(v1), f2h(v2), f2h(v3));
    *reinterpret_cast<ushort4*>(xh + (size_t)b * 256 + q * 4) = u;
    if (q == 0) idx[b] = (int)rintf(xr[N_INP] * 255.0f);
  } else {
    int t = (blockIdx.x - 8192) * 256 + threadIdx.x; // 65536 threads
    float4 a = reinterpret_cast<const float4*>(W1)[t];
    float4 b = reinterpret_cast<const float4*>(W2)[t];
    reinterpret_cast<ushort4*>(w1h)[t] = make_ushort4(f2h(a.x), f2h(a.y), f2h(a.z), f2h(a.w));
    reinterpret_cast<ushort4*>(w2h)[t] = make_ushort4(f2h(b.x), f2h(b.y), f2h(b.z), f2h(b.w));
  }
}

// ---- C[M,N] = epi(A[M,K] @ Bw[N,K]^T + bias), f16 output ----
// RELU=1 for GEMM1 -> h; RELU=0 for GEMM2 -> x_ (f16)
template <int RELU>
__global__ __launch_bounds__(256, 2) void gemm_bt(
    const ushort* __restrict__ A, const ushort* __restrict__ Bw,
    const float* __restrict__ bias, ushort* __restrict__ C,
    int M, int N, int K, int ntN) {
  __shared__ ushort As[2][128 * 64];
  __shared__ ushort Bs[2][128 * 64];
  const int tid = threadIdx.x;
  const int w = tid >> 6, l = tid & 63;
  const int tm = blockIdx.x / ntN, tn = blockIdx.x % ntN;
  const int wm = w >> 1, wn = w & 1;
  const char* Ab = (const char*)(A + (size_t)tm * 128 * K);
  const char* Bb = (const char*)(Bw + (size_t)tn * 128 * K);
  const int sA = K * 2;
  const int lrow = l >> 3;
  const int lcol = (l & 7) * 16;

  f32x4 acc[4][4];
#pragma unroll
  for (int i = 0; i < 4; ++i)
#pragma unroll
    for (int j = 0; j < 4; ++j) acc[i][j] = {0.f, 0.f, 0.f, 0.f};

  const int nkt = K / 64;
  {  // prologue stage kt=0
    const char* ga = Ab + lrow * sA + lcol;
    const char* gb = Bb + lrow * sA + lcol;
#pragma unroll
    for (int i = 0; i < 4; ++i) {
      int c = w * 4 + i;
      async_copy16(ga + c * 8 * sA, (char*)&As[0][0] + c * 1024);
      async_copy16(gb + c * 8 * sA, (char*)&Bs[0][0] + c * 1024);
    }
  }
  __syncthreads();

  const int arow = wm * 64 + (l & 15);
  const int brow = wn * 64 + (l & 15);
  const int koff = (l >> 4) * 8;

  for (int kt = 0; kt < nkt; ++kt) {
    const int buf = kt & 1;
    if (kt + 1 < nkt) {
      const char* ga = Ab + (kt + 1) * 128 + lrow * sA + lcol;
      const char* gb = Bb + (kt + 1) * 128 + lrow * sA + lcol;
#pragma unroll
      for (int i = 0; i < 4; ++i) {
        int c = w * 4 + i;
        async_copy16(ga + c * 8 * sA, (char*)&As[buf ^ 1][0] + c * 1024);
        async_copy16(gb + c * 8 * sA, (char*)&Bs[buf ^ 1][0] + c * 1024);
      }
    }
#pragma unroll
    for (int ks = 0; ks < 2; ++ks) {
      f16x8 af[4], bfr[4];
#pragma unroll
      for (int mi = 0; mi < 4; ++mi)
        af[mi] = *(const f16x8*)&As[buf][(arow + mi * 16) * 64 + ks * 32 + koff];
#pragma unroll
      for (int ni = 0; ni < 4; ++ni)
        bfr[ni] = *(const f16x8*)&Bs[buf][(brow + ni * 16) * 64 + ks * 32 + koff];
#pragma unroll
      for (int mi = 0; mi < 4; ++mi)
#pragma unroll
        for (int ni = 0; ni < 4; ++ni)
          acc[mi][ni] = __builtin_amdgcn_mfma_f32_16x16x32_f16(
              af[mi], bfr[ni], acc[mi][ni], 0, 0, 0);
    }
    __syncthreads();
  }

  // epilogue: C/D layout col=lane&15, row=(lane>>4)*4+r
  const int grow0 = tm * 128 + wm * 64 + (l >> 4) * 4;
  const int gcol0 = tn * 128 + wn * 64 + (l & 15);
#pragma unroll
  for (int ni = 0; ni < 4; ++ni) {
    const int col = gcol0 + ni * 16;
    const float bv = bias[col];
#pragma unroll
    for (int mi = 0; mi < 4; ++mi) {
      const int row = grow0 + mi * 16;
#pragma unroll
      for (int r = 0; r < 4; ++r) {
        float v = acc[mi][ni][r] + bv;
        if (RELU) v = fmaxf(v, 0.f);
        C[(size_t)(row + r) * N + col] = f2h(v);
      }
    }
  }
}

// ---- convex fixed-point (100 iters) + gather ----
// y-space: y = z + param; iteration is exactly y_i <- min(y_i, 0.5*(y_{i-1}+y_{i+1}));
// result = y. Boundary feats 0,255 never update (sentinel makes mid huge).
// 8 feats/lane, 32 lanes/row, 2 rows/wave.
__global__ __launch_bounds__(256) void convex_gather(
    const ushort* __restrict__ xqh, const int* __restrict__ idx,
    float* __restrict__ out) {
  const int w = threadIdx.x >> 6, l = threadIdx.x & 63;
  const int half = l >> 5, li = l & 31;
  const int b = blockIdx.x * 8 + w * 2 + half;
  f16x8 hv = *reinterpret_cast<const f16x8*>(xqh + (size_t)b * 256 + li * 8);
  float y0 = (float)hv[0], y1 = (float)hv[1], y2 = (float)hv[2], y3 = (float)hv[3];
  float y4 = (float)hv[4], y5 = (float)hv[5], y6 = (float)hv[6], y7 = (float)hv[7];
  // sentinels: feature 0 (li==0, y0) and feature 255 (li==31, y7) must never drop
  const float bL = (li == 0) ? 3.0e38f : 0.0f;
  const float bR = (li == 31) ? 3.0e38f : 0.0f;
#pragma unroll 2
  for (int it = 0; it < N_IT; ++it) {
    float L = __shfl_up(y7, 1) + bL;    // feat 8*li-1 (lane 32: cross-row, masked)
    float R = __shfl_down(y0, 1) + bR;  // feat 8*li+8 (lane 31: cross-row, masked)
    float m0 = 0.5f * (L + y1);
    float m1 = 0.5f * (y0 + y2);
    float m2 = 0.5f * (y1 + y3);
    float m3 = 0.5f * (y2 + y4);
    float m4 = 0.5f * (y3 + y5);
    float m5 = 0.5f * (y4 + y6);
    float m6 = 0.5f * (y5 + y7);
    float m7 = 0.5f * (y6 + R);
    y0 = fminf(y0, m0);
    y1 = fminf(y1, m1);
    y2 = fminf(y2, m2);
    y3 = fminf(y3, m3);
    y4 = fminf(y4, m4);
    y5 = fminf(y5, m5);
    y6 = fminf(y6, m6);
    y7 = fminf(y7, m7);
  }
  const int ii = idx[b];  // uniform within each 32-lane half
  float s0 = (ii & 1) ? y1 : y0;
  float s1 = (ii & 1) ? y3 : y2;
  float s2 = (ii & 1) ? y5 : y4;
  float s3 = (ii & 1) ? y7 : y6;
  float t0 = (ii & 2) ? s1 : s0;
  float t1 = (ii & 2) ? s3 : s2;
  float r = (ii & 4) ? t1 : t0;
  float v = __shfl(r, half * 32 + (ii >> 3));
  if (li == 0) out[b] = v;
}

extern "C" void kernel_launch(void* const* d_in, const int* in_sizes, int n_in,
                              void* d_out, int out_size, void* d_ws, size_t ws_size,
                              hipStream_t stream) {
  const float* x = (const float*)d_in[0];
  const float* W1 = (const float*)d_in[1];
  const float* b1 = (const float*)d_in[2];
  const float* W2 = (const float*)d_in[3];
  const float* b2 = (const float*)d_in[4];
  float* out = (float*)d_out;

  // workspace layout (16B-aligned)
  char* ws = (char*)d_ws;
  ushort* xh  = (ushort*)ws;                    // 16,777,216 B  x f16 [B,256]
  ushort* w1h = (ushort*)(ws + 16777216);       //    524,288 B
  ushort* w2h = (ushort*)(ws + 17301504);       //    524,288 B
  int*    idx = (int*)  (ws + 17825792);        //    131,072 B
  ushort* xqh = (ushort*)(ws + 17956864);       // 16,777,216 B  x_ f16 [B,256]
  ushort* h   = (ushort*)(ws + 34734080);       // chunk*2048 B  h f16 [chunk,1024]

  const size_t fixed = 34734080;
  int chunk = 2048;
  if (ws_size >= fixed + (size_t)32768 * 2048) chunk = 32768;
  else if (ws_size >= fixed + (size_t)16384 * 2048) chunk = 16384;
  else if (ws_size >= fixed + (size_t)8192 * 2048) chunk = 8192;
  else if (ws_size >= fixed + (size_t)4096 * 2048) chunk = 4096;

  prep_kernel<<<8448, 256, 0, stream>>>(x, W1, W2, xh, w1h, w2h, idx);

  for (int m0 = 0; m0 < B_ROWS; m0 += chunk) {
    int curM = (B_ROWS - m0 < chunk) ? (B_ROWS - m0) : chunk;
    dim3 g1((curM / 128) * (N_HID / 128));
    gemm_bt<1><<<g1, 256, 0, stream>>>(xh + (size_t)m0 * 256, w1h, b1, h,
                                       curM, N_HID, N_INP, N_HID / 128);
    dim3 g2((curM / 128) * (NF / 128));
    gemm_bt<0><<<g2, 256, 0, stream>>>(h, w2h, b2, xqh + (size_t)m0 * 256,
                                       curM, NF, N_HID, NF / 128);
  }
  convex_gather<<<B_ROWS / 8, 256, 0, stream>>>(xqh, idx, out);
}